// Round 6
// baseline (110.182 us; speedup 1.0000x reference)
//
#include <hip/hip_runtime.h>
#include <hip/hip_bf16.h>

#define BATCH 65536
#define IN    64
#define H     128
#define NA    16
#define NBLK  256      // 256 rows per block
#define TPB   256      // 4 waves; each wave owns 64 batch rows (4 col-sets)

// ws image (uint4 granules): w0[0,3072) w1[3072,9216) wph[9216,9728)
// biases [9728,9920) = 768 floats (b0 384, b1 384). Total 158.7 KB (bf16 -> L2-resident).
#define OW1   3072
#define OPH   9216
#define OBIAS 9728
#define NTOT  9920

typedef __bf16 bf16x8 __attribute__((ext_vector_type(8)));
typedef float  f32x4  __attribute__((ext_vector_type(4)));
typedef float  f32x2  __attribute__((ext_vector_type(2)));

union Frag { uint4 u; bf16x8 v; };
struct F32x8 { float4 a, b; };

#define EXP2F(v) __builtin_amdgcn_exp2f(v)
#define RCPF(v)  __builtin_amdgcn_rcpf(v)
#define K1 1.442695041f   // log2(e)
#define K2 2.885390082f   // 2*log2(e)

__device__ __forceinline__ F32x8 ld8f(const float* p) {
    F32x8 r;
    r.a = *reinterpret_cast<const float4*>(p);
    r.b = *reinterpret_cast<const float4*>(p + 4);
    return r;
}
__device__ __forceinline__ Frag cvt8(F32x8 x) {
    Frag f;
    f.v[0]=(__bf16)x.a.x; f.v[1]=(__bf16)x.a.y; f.v[2]=(__bf16)x.a.z; f.v[3]=(__bf16)x.a.w;
    f.v[4]=(__bf16)x.b.x; f.v[5]=(__bf16)x.b.y; f.v[6]=(__bf16)x.b.z; f.v[7]=(__bf16)x.b.w;
    return f;
}
__device__ __forceinline__ Frag cvt44(float4 a, float4 b) {
    Frag f;
    f.v[0]=(__bf16)a.x; f.v[1]=(__bf16)a.y; f.v[2]=(__bf16)a.z; f.v[3]=(__bf16)a.w;
    f.v[4]=(__bf16)b.x; f.v[5]=(__bf16)b.y; f.v[6]=(__bf16)b.z; f.v[7]=(__bf16)b.w;
    return f;
}
__device__ __forceinline__ unsigned pk2(float lo, float hi) {
    unsigned short l = __builtin_bit_cast(unsigned short, (__bf16)lo);
    unsigned short h = __builtin_bit_cast(unsigned short, (__bf16)hi);
    return (unsigned)l | ((unsigned)h << 16);
}

// Paired activation, packed-f32 math, no clamps (bound-safe: |gate0|<=30,
// |gate1|<=11.3 << 44 overflow). h = sigmoid(o)*tanh(sigmoid(i)*tanh(g)).
__device__ __forceinline__ unsigned lstm_h2(f32x2 ip, f32x2 gp, f32x2 op) {
    const f32x2 ai = ip * (-K1);
    const f32x2 ag = gp * ( K2);
    f32x2 Ei; Ei[0]=EXP2F(ai[0]); Ei[1]=EXP2F(ai[1]);
    f32x2 Eg; Eg[0]=EXP2F(ag[0]); Eg[1]=EXP2F(ag[1]);
    const f32x2 dn = (Ei + 1.0f) * (Eg + 1.0f);
    f32x2 rd; rd[0]=RCPF(dn[0]); rd[1]=RCPF(dn[1]);
    const f32x2 c2 = (Eg - 1.0f) * rd;
    const f32x2 ao = op * (-K1);
    const f32x2 ac = c2 * ( K2);
    f32x2 Eo; Eo[0]=EXP2F(ao[0]); Eo[1]=EXP2F(ao[1]);
    f32x2 Ec; Ec[0]=EXP2F(ac[0]); Ec[1]=EXP2F(ac[1]);
    const f32x2 dh = (Eo + 1.0f) * (Ec + 1.0f);
    f32x2 rh; rh[0]=RCPF(dh[0]); rh[1]=RCPF(dh[1]);
    const f32x2 h = (Ec - 1.0f) * rh;
    return pk2(h[0], h[1]);
}

__device__ __forceinline__ int igo_row(int j) {        // j = g*128+h -> src row
    const int g = j >> 7, h = j & 127;
    return h + ((g == 0) ? 0 : (g + 1) * 128);         // i,g,o -> 0, 2H, 3H
}

// ===========================================================================
// R6: NO-LDS structure. Every prior variant (R0-R5, all ~46us warm despite
// structural diversity) shared: 155KB LDS weight image -> 1 block/CU,
// scattered staging prologue, full-drain barrier, LDS frag re-reads. R6
// deletes all of it: prep kernel builds bf16 pi-permuted frag images in d_ws
// (155 KB -> L2-resident per XCD); main kernel reads A-frags DIRECTLY from
// global/L2 (each frag load = 16x 64B lines, fully utilized, 4 lanes/line).
// Zero LDS, zero barriers, reuse=4 (64 rows/wave) -> 0.6 MB L2/CU ~= 4.5us.
// Compute math identical to R5 (packed acts, bias as MFMA C-in, pi-trick).
// MFMA layouts: A: M-row=lane&15, k=quad*8+j. B: N-col=lane&15, k=quad*8+j.
//               D: N-col=lane&15, M-row=quad*4+reg.
// pi-trick: layer-(l+1) B-frag for k-tile kt := packed h-words {hw[4kt+j2]};
// w1/wph granule (row n, slot s=kt*4+qq) = [W[n][32kt+4qq..+3],
// W[n][32kt+16+4qq..+3]] as bf16.  w0 granule (n,s) = W[n][8s..8s+7] (linear).
// ===========================================================================
__global__ __launch_bounds__(256)
void lstm_prep(const float* __restrict__ Wih0,
               const float* __restrict__ bih0,
               const float* __restrict__ bhh0,
               const float* __restrict__ Wih1,
               const float* __restrict__ bih1,
               const float* __restrict__ bhh1,
               const float* __restrict__ Wp,
               const float* __restrict__ Wv,
               uint4* __restrict__ ws)
{
    const int G = blockIdx.x * 256 + threadIdx.x;
    if (G < OW1) {                       // ---- w0 image: row j, slot s (linear k)
        const int j = G >> 3, s = G & 7;
        const int srow = igo_row(j);
        Frag f = cvt8(ld8f(Wih0 + (size_t)srow * IN + s * 8));
        ws[(j << 3) + s] = f.u;
    } else if (G < OPH) {                // ---- w1 image (pi-permuted) ----
        const int t = G - OW1;
        const int j = t >> 4, s = t & 15;
        const int srow = igo_row(j);
        const int kt = s >> 2, qq = s & 3;
        const float* pA = Wih1 + (size_t)srow * H + kt * 32 + qq * 4;
        Frag f = cvt44(*reinterpret_cast<const float4*>(pA),
                       *reinterpret_cast<const float4*>(pA + 16));
        ws[OW1 + (j << 4) + s] = f.u;
    } else if (G < OBIAS) {              // ---- head image (pi-permuted) ----
        const int t = G - OPH;
        const int j = t >> 4, s = t & 15;
        const int kt = s >> 2, qq = s & 3;
        Frag f;
        if (j <= 16) {
            const float* base = (j < 16) ? (Wp + (size_t)j * H) : Wv;
            const float* pA = base + kt * 32 + qq * 4;
            f = cvt44(*reinterpret_cast<const float4*>(pA),
                      *reinterpret_cast<const float4*>(pA + 16));
        } else {
            f.u = make_uint4(0u, 0u, 0u, 0u);
        }
        ws[OPH + (j << 4) + s] = f.u;
    } else if (G < NTOT) {               // ---- biases, pre-summed, igo ----
        const int fbase = (G - OBIAS) * 4;
        float4 r;
#pragma unroll
        for (int e = 0; e < 4; ++e) {
            const int i = fbase + e;
            float v;
            if (i < 384) { const int sr = igo_row(i);        v = bih0[sr] + bhh0[sr]; }
            else         { const int sr = igo_row(i - 384);  v = bih1[sr] + bhh1[sr]; }
            reinterpret_cast<float*>(&r)[e] = v;
        }
        ws[G] = __builtin_bit_cast(uint4, r);
    }
}

__global__ __launch_bounds__(TPB, 2)
void lstm_fused(const float* __restrict__ x,
                const uint4* __restrict__ ws,
                const float* __restrict__ bp,
                const float* __restrict__ bv,
                float* __restrict__ out)
{
    const int tid  = threadIdx.x;
    const int wave = tid >> 6;
    const int lane = tid & 63;
    const int q    = lane >> 4;
    const int m    = lane & 15;
    const int rbase = blockIdx.x * 256 + wave * 64;      // 64 rows per wave
    const f32x4 vzero = {0.f, 0.f, 0.f, 0.f};

    // ---- x loads (HBM) ----
    F32x8 xr[4][2];
#pragma unroll
    for (int s4 = 0; s4 < 4; ++s4) {
        const float* xp = x + (size_t)(rbase + s4 * 16 + m) * IN + q * 8;
        xr[s4][0] = ld8f(xp);
        xr[s4][1] = ld8f(xp + 32);
    }
    const float4 bpr = *reinterpret_cast<const float4*>(bp + q * 4);
    const float  bvv = bv[0];
    const float* bias = reinterpret_cast<const float*>(ws + OBIAS);

    Frag xb[4][2];
#pragma unroll
    for (int s4 = 0; s4 < 4; ++s4) {
        xb[s4][0] = cvt8(xr[s4][0]);
        xb[s4][1] = cvt8(xr[s4][1]);
    }

    // ===== Layer 0: frags straight from L2; bias as MFMA C-in ==============
    unsigned hw0[4][16];
#pragma unroll
    for (int nc = 0; nc < 8; ++nc) {
        const f32x4 bI = *reinterpret_cast<const f32x4*>(bias +       nc * 16 + q * 4);
        const f32x4 bG = *reinterpret_cast<const f32x4*>(bias + 128 + nc * 16 + q * 4);
        const f32x4 bO = *reinterpret_cast<const f32x4*>(bias + 256 + nc * 16 + q * 4);
        f32x4 acc[3][4];
#pragma unroll
        for (int s4 = 0; s4 < 4; ++s4) {
            acc[0][s4] = bI; acc[1][s4] = bG; acc[2][s4] = bO;
        }
#pragma unroll
        for (int g = 0; g < 3; ++g) {
            const int n = g * 128 + nc * 16 + m;
#pragma unroll
            for (int kt = 0; kt < 2; ++kt) {
                Frag a; a.u = ws[(n << 3) + kt * 4 + q];
#pragma unroll
                for (int s4 = 0; s4 < 4; ++s4)
                    acc[g][s4] = __builtin_amdgcn_mfma_f32_16x16x32_bf16(
                        a.v, xb[s4][kt].v, acc[g][s4], 0, 0, 0);
            }
        }
#pragma unroll
        for (int s4 = 0; s4 < 4; ++s4)
#pragma unroll
            for (int u = 0; u < 2; ++u) {
                const f32x2 ip = {acc[0][s4][2*u], acc[0][s4][2*u+1]};
                const f32x2 gp = {acc[1][s4][2*u], acc[1][s4][2*u+1]};
                const f32x2 op = {acc[2][s4][2*u], acc[2][s4][2*u+1]};
                hw0[s4][nc * 2 + u] = lstm_h2(ip, gp, op);
            }
    }

    // ===== Layer 1: B-frags = hw0 words (pi-absorbed) =======================
    unsigned hw1[4][16];
#pragma unroll
    for (int nc = 0; nc < 8; ++nc) {
        const f32x4 bI = *reinterpret_cast<const f32x4*>(bias + 384 +       nc * 16 + q * 4);
        const f32x4 bG = *reinterpret_cast<const f32x4*>(bias + 384 + 128 + nc * 16 + q * 4);
        const f32x4 bO = *reinterpret_cast<const f32x4*>(bias + 384 + 256 + nc * 16 + q * 4);
        f32x4 acc[3][4];
#pragma unroll
        for (int s4 = 0; s4 < 4; ++s4) {
            acc[0][s4] = bI; acc[1][s4] = bG; acc[2][s4] = bO;
        }
#pragma unroll
        for (int kt = 0; kt < 4; ++kt) {
            Frag b[4];
#pragma unroll
            for (int s4 = 0; s4 < 4; ++s4)
                b[s4].u = make_uint4(hw0[s4][4*kt], hw0[s4][4*kt+1],
                                     hw0[s4][4*kt+2], hw0[s4][4*kt+3]);
#pragma unroll
            for (int g = 0; g < 3; ++g) {
                const int n = g * 128 + nc * 16 + m;
                Frag a; a.u = ws[OW1 + (n << 4) + kt * 4 + q];
#pragma unroll
                for (int s4 = 0; s4 < 4; ++s4)
                    acc[g][s4] = __builtin_amdgcn_mfma_f32_16x16x32_bf16(
                        a.v, b[s4].v, acc[g][s4], 0, 0, 0);
            }
        }
#pragma unroll
        for (int s4 = 0; s4 < 4; ++s4)
#pragma unroll
            for (int u = 0; u < 2; ++u) {
                const f32x2 ip = {acc[0][s4][2*u], acc[0][s4][2*u+1]};
                const f32x2 gp = {acc[1][s4][2*u], acc[1][s4][2*u+1]};
                const f32x2 op = {acc[2][s4][2*u], acc[2][s4][2*u+1]};
                hw1[s4][nc * 2 + u] = lstm_h2(ip, gp, op);
            }
    }

    // ===== Heads: tile0 rows = policy, tile1 row16 = value ==================
    f32x4 ap[4], av[4];
#pragma unroll
    for (int s4 = 0; s4 < 4; ++s4) { ap[s4] = vzero; av[s4] = vzero; }
#pragma unroll
    for (int kt = 0; kt < 4; ++kt) {
        Frag a0; a0.u = ws[OPH + ( m       << 4) + kt * 4 + q];
        Frag a1; a1.u = ws[OPH + ((16 + m) << 4) + kt * 4 + q];
#pragma unroll
        for (int s4 = 0; s4 < 4; ++s4) {
            Frag b; b.u = make_uint4(hw1[s4][4*kt], hw1[s4][4*kt+1],
                                     hw1[s4][4*kt+2], hw1[s4][4*kt+3]);
            ap[s4] = __builtin_amdgcn_mfma_f32_16x16x32_bf16(a0.v, b.v, ap[s4], 0, 0, 0);
            av[s4] = __builtin_amdgcn_mfma_f32_16x16x32_bf16(a1.v, b.v, av[s4], 0, 0, 0);
        }
    }
#pragma unroll
    for (int s4 = 0; s4 < 4; ++s4) {
        const int row = rbase + s4 * 16 + m;
        // policy: D col = batch m, row = action q*4+r -> one dwordx4 per lane
        f32x4 po;
        po[0] = ap[s4][0] + bpr.x; po[1] = ap[s4][1] + bpr.y;
        po[2] = ap[s4][2] + bpr.z; po[3] = ap[s4][3] + bpr.w;
        *reinterpret_cast<f32x4*>(out + (size_t)row * NA + q * 4) = po;
        // value lives at tile1 in-tile row 0 -> q==0, reg 0
        if (q == 0) out[(size_t)BATCH * NA + row] = av[s4][0] + bvv;
    }
}

extern "C" void kernel_launch(void* const* d_in, const int* in_sizes, int n_in,
                              void* d_out, int out_size, void* d_ws, size_t ws_size,
                              hipStream_t stream) {
    // setup_inputs order: x, Wih0, Whh0, bih0, bhh0, Wih1, Whh1, bih1, bhh1, Wp, bp, Wv, bv
    // Whh0 (idx 2) / Whh1 (idx 6) dead (h_prev = 0); f-gate dead (c_prev = 0).
    uint4* ws = (uint4*)d_ws;            // 158.7 KB image; rebuilt every launch
    lstm_prep<<<dim3((NTOT + 255) / 256), dim3(256), 0, stream>>>(
        (const float*)d_in[1], (const float*)d_in[3], (const float*)d_in[4],
        (const float*)d_in[5], (const float*)d_in[7], (const float*)d_in[8],
        (const float*)d_in[9], (const float*)d_in[11], ws);
    lstm_fused<<<dim3(NBLK), dim3(TPB), 0, stream>>>(
        (const float*)d_in[0], ws,
        (const float*)d_in[10], (const float*)d_in[12], (float*)d_out);
}

// Round 8
// 105.886 us; speedup vs baseline: 1.0406x; 1.0406x over previous
//
#include <hip/hip_runtime.h>
#include <hip/hip_bf16.h>

#define BATCH 65536
#define IN    64
#define H     128
#define NA    16
#define NBLK  256      // 1 block per CU, 155 KB LDS
#define TPB   512      // 8 waves; each wave owns 32 batch rows (2 column-sets)

typedef __bf16 bf16x8 __attribute__((ext_vector_type(8)));
typedef float  f32x4  __attribute__((ext_vector_type(4)));
typedef float  f32x2  __attribute__((ext_vector_type(2)));

union Frag { uint4 u; bf16x8 v; };
struct F32x8 { float4 a, b; };

#define EXP2F(v) __builtin_amdgcn_exp2f(v)
#define RCPF(v)  __builtin_amdgcn_rcpf(v)
#define K1 1.442695041f   // log2(e)
#define K2 2.885390082f   // 2*log2(e)

__device__ __forceinline__ F32x8 ld8f(const float* p) {
    F32x8 r;
    r.a = *reinterpret_cast<const float4*>(p);
    r.b = *reinterpret_cast<const float4*>(p + 4);
    return r;
}
__device__ __forceinline__ Frag cvt8(F32x8 x) {
    Frag f;
    f.v[0]=(__bf16)x.a.x; f.v[1]=(__bf16)x.a.y; f.v[2]=(__bf16)x.a.z; f.v[3]=(__bf16)x.a.w;
    f.v[4]=(__bf16)x.b.x; f.v[5]=(__bf16)x.b.y; f.v[6]=(__bf16)x.b.z; f.v[7]=(__bf16)x.b.w;
    return f;
}
__device__ __forceinline__ Frag cvt44(float4 a, float4 b) {
    Frag f;
    f.v[0]=(__bf16)a.x; f.v[1]=(__bf16)a.y; f.v[2]=(__bf16)a.z; f.v[3]=(__bf16)a.w;
    f.v[4]=(__bf16)b.x; f.v[5]=(__bf16)b.y; f.v[6]=(__bf16)b.z; f.v[7]=(__bf16)b.w;
    return f;
}
__device__ __forceinline__ unsigned pk2(float lo, float hi) {
    unsigned short l = __builtin_bit_cast(unsigned short, (__bf16)lo);
    unsigned short h = __builtin_bit_cast(unsigned short, (__bf16)hi);
    return (unsigned)l | ((unsigned)h << 16);
}

// Paired activation, packed-f32 math (v_pk_* on gfx950), NO clamps.
// Safety: |gate0| <= 64*5.3*0.0884 ~= 30, |gate1| <= 128*1*0.0884 ~= 11.3,
// both << 44 (f32 exp2 overflow at arg 128/K2); Eg finite -> no inf*0 NaN.
// h = sigmoid(o)*tanh(sigmoid(i)*tanh(g)); f-gate dead (c_prev=0).
__device__ __forceinline__ unsigned lstm_h2(f32x2 ip, f32x2 gp, f32x2 op) {
    const f32x2 ai = ip * (-K1);
    const f32x2 ag = gp * ( K2);
    f32x2 Ei; Ei[0]=EXP2F(ai[0]); Ei[1]=EXP2F(ai[1]);
    f32x2 Eg; Eg[0]=EXP2F(ag[0]); Eg[1]=EXP2F(ag[1]);
    const f32x2 dn = (Ei + 1.0f) * (Eg + 1.0f);
    f32x2 rd; rd[0]=RCPF(dn[0]); rd[1]=RCPF(dn[1]);
    const f32x2 c2 = (Eg - 1.0f) * rd;
    const f32x2 ao = op * (-K1);
    const f32x2 ac = c2 * ( K2);
    f32x2 Eo; Eo[0]=EXP2F(ao[0]); Eo[1]=EXP2F(ao[1]);
    f32x2 Ec; Ec[0]=EXP2F(ac[0]); Ec[1]=EXP2F(ac[1]);
    const f32x2 dh = (Eo + 1.0f) * (Ec + 1.0f);
    f32x2 rh; rh[0]=RCPF(dh[0]); rh[1]=RCPF(dh[1]);
    const f32x2 h = (Ec - 1.0f) * rh;
    return pk2(h[0], h[1]);
}

// ===========================================================================
// FINAL (session best, 106.83us): R2 structure + R5 activation slimming.
// Session findings (R0-R6, six structurally independent variants):
//  - single-kernel variants pin at 106.8-107.3us; dual-kernel +3us (launch);
//  - invariant to: occupancy (R2), code size (R3), staging path (R4),
//    VALU count (R5), LDS/barrier existence (R6);
//  - harness re-poison fills (268MB @ 79% HBM peak, 43us each) + graph gaps
//    dominate the total; kernel-side headroom exhausted.
// Structure: 1 block/CU; weights staged once to LDS (bf16, pi-permuted,
// XOR-swizzled); ONE barrier; barrier-free transposed compute chain
// (gates^T = W x act^T), activations stay lane-local across all 3 GEMMs.
// MFMA layouts: A: M-row=lane&15, k=quad*8+j. B: N-col=lane&15, k=quad*8+j.
//               D: N-col=lane&15, M-row=quad*4+reg.
// pi-trick: next layer's B-frag for k-tile kt := packed h-words {hw[4kt+j2]};
// Wih1/Wp columns stored permuted by the same bijection pi at staging time ->
// no shuffles / LDS round-trips / barriers between layers.
// Staging granule (row n, slot s; kt=s>>2, qq=s&3) = [W[n][32kt+4qq..+3],
// W[n][32kt+16+4qq..+3]].  Slot XOR-swizzle (s ^ (n&7)) -> 2-way reads (free).
// ===========================================================================
__global__ __launch_bounds__(TPB, 2)
void lstm_fused(const float* __restrict__ x,
                const float* __restrict__ Wih0,
                const float* __restrict__ bih0,
                const float* __restrict__ bhh0,
                const float* __restrict__ Wih1,
                const float* __restrict__ bih1,
                const float* __restrict__ bhh1,
                const float* __restrict__ Wp,
                const float* __restrict__ bp,
                const float* __restrict__ Wv,
                const float* __restrict__ bv,
                float* __restrict__ out)
{
    __shared__ __align__(16) uint4 w0s[384 * 8];   // 48 KB  Wih0 igo, linear k
    __shared__ __align__(16) uint4 w1s[384 * 16];  // 96 KB  Wih1 igo, pi-permuted k
    __shared__ __align__(16) uint4 wph[32 * 16];   //  8 KB  rows 0-15 Wp, 16 Wv, 17-31 zero
    __shared__ float b0s[384];                     // bih0+bhh0, igo-packed
    __shared__ float b1s[384];                     // bih1+bhh1

    const int tid  = threadIdx.x;
    const int wave = tid >> 6;
    const int lane = tid & 63;
    const int q    = lane >> 4;
    const int m    = lane & 15;
    const int rbase = blockIdx.x * 256 + wave * 32;      // 32 rows per wave
    const f32x4 vzero = {0.f, 0.f, 0.f, 0.f};

    // ---- x prefetch (HBM, longest latency) issued before weight staging ----
    F32x8 xr[2][2];
#pragma unroll
    for (int s2 = 0; s2 < 2; ++s2) {
        const float* xp = x + (size_t)(rbase + s2 * 16 + m) * IN + q * 8;
        xr[s2][0] = ld8f(xp);
        xr[s2][1] = ld8f(xp + 32);
    }
    const float4 bpr = *reinterpret_cast<const float4*>(bp + q * 4);
    const float  bvv = bv[0];

    // ---- Stage Wih0: 3072 granules (row j = g*128+h, 8 slots of 8 cols) ----
#pragma unroll
    for (int r = 0; r < 6; ++r) {
        const int idx = tid + (r << 9);
        const int j = idx >> 3, s = idx & 7;
        const int g = j >> 7, h = j & 127;
        const int srow = h + ((g == 0) ? 0 : (g + 1) * 128);   // i,g,o -> 0,2H,3H
        Frag f = cvt8(ld8f(Wih0 + (size_t)srow * IN + s * 8));
        w0s[(j << 3) + (s ^ (j & 7))] = f.u;
    }
    // ---- Stage Wih1 pi-permuted: 6144 granules (16 slots per row) ----
#pragma unroll
    for (int r = 0; r < 12; ++r) {
        const int idx = tid + (r << 9);
        const int j = idx >> 4, s = idx & 15;
        const int g = j >> 7, h = j & 127;
        const int srow = h + ((g == 0) ? 0 : (g + 1) * 128);
        const int kt = s >> 2, qq = s & 3;
        const float* pA = Wih1 + (size_t)srow * H + kt * 32 + qq * 4;
        Frag f = cvt44(*reinterpret_cast<const float4*>(pA),
                       *reinterpret_cast<const float4*>(pA + 16));
        w1s[(j << 4) + (s ^ (j & 7))] = f.u;
    }
    // ---- Stage heads pi-permuted (+ zero-fill rows 17-31): 512 granules ----
    {
        const int j = tid >> 4, s = tid & 15;
        const int kt = s >> 2, qq = s & 3;
        Frag f;
        if (j <= 16) {
            const float* base = (j < 16) ? (Wp + (size_t)j * H) : Wv;
            const float* pA = base + kt * 32 + qq * 4;
            f = cvt44(*reinterpret_cast<const float4*>(pA),
                      *reinterpret_cast<const float4*>(pA + 16));
        } else {
            f.u = make_uint4(0u, 0u, 0u, 0u);
        }
        wph[(j << 4) + (s ^ (j & 7))] = f.u;
    }
    // ---- Stage biases (igo-packed, bih+bhh pre-summed) ----
#pragma unroll
    for (int r = 0; r < 2; ++r) {
        const int t = tid + (r << 9);
        if (t < 384) {
            const int g = t >> 7, h = t & 127;
            const int srow = h + ((g == 0) ? 0 : (g + 1) * 128);
            b0s[t] = bih0[srow] + bhh0[srow];
        } else if (t < 768) {
            const int tt = t - 384;
            const int g = tt >> 7, h = tt & 127;
            const int srow = h + ((g == 0) ? 0 : (g + 1) * 128);
            b1s[tt] = bih1[srow] + bhh1[srow];
        }
    }

    __syncthreads();   // the ONLY barrier in the kernel

    const int swz = m & 7;
    Frag xb[2][2];
#pragma unroll
    for (int s2 = 0; s2 < 2; ++s2) {
        xb[s2][0] = cvt8(xr[s2][0]);
        xb[s2][1] = cvt8(xr[s2][1]);
    }

    // ===== Layer 0: D1 = Wih0 x x^T, 16 hidden units x 2 col-sets at a time =
    unsigned hw0[2][16];
#pragma unroll
    for (int nc = 0; nc < 8; ++nc) {
        const f32x4 bI = *reinterpret_cast<const f32x4*>(b0s +       nc * 16 + q * 4);
        const f32x4 bG = *reinterpret_cast<const f32x4*>(b0s + 128 + nc * 16 + q * 4);
        const f32x4 bO = *reinterpret_cast<const f32x4*>(b0s + 256 + nc * 16 + q * 4);
        f32x4 acc[3][2];
#pragma unroll
        for (int s2 = 0; s2 < 2; ++s2) {      // bias as MFMA C-in
            acc[0][s2] = bI; acc[1][s2] = bG; acc[2][s2] = bO;
        }
#pragma unroll
        for (int g = 0; g < 3; ++g) {
            const int n = g * 128 + nc * 16 + m;
#pragma unroll
            for (int kt = 0; kt < 2; ++kt) {
                Frag a; a.u = w0s[(n << 3) + ((kt * 4 + q) ^ swz)];
#pragma unroll
                for (int s2 = 0; s2 < 2; ++s2)
                    acc[g][s2] = __builtin_amdgcn_mfma_f32_16x16x32_bf16(
                        a.v, xb[s2][kt].v, acc[g][s2], 0, 0, 0);
            }
        }
#pragma unroll
        for (int s2 = 0; s2 < 2; ++s2)
#pragma unroll
            for (int u = 0; u < 2; ++u) {
                const f32x2 ip = {acc[0][s2][2*u], acc[0][s2][2*u+1]};
                const f32x2 gp = {acc[1][s2][2*u], acc[1][s2][2*u+1]};
                const f32x2 op = {acc[2][s2][2*u], acc[2][s2][2*u+1]};
                hw0[s2][nc * 2 + u] = lstm_h2(ip, gp, op);
            }
    }

    // ===== Layer 1: D2 = Wih1p x h0^T (B-frags = hw0 words, pi-absorbed) ====
    unsigned hw1[2][16];
#pragma unroll
    for (int nc = 0; nc < 8; ++nc) {
        const f32x4 bI = *reinterpret_cast<const f32x4*>(b1s +       nc * 16 + q * 4);
        const f32x4 bG = *reinterpret_cast<const f32x4*>(b1s + 128 + nc * 16 + q * 4);
        const f32x4 bO = *reinterpret_cast<const f32x4*>(b1s + 256 + nc * 16 + q * 4);
        f32x4 acc[3][2];
#pragma unroll
        for (int s2 = 0; s2 < 2; ++s2) {      // bias as MFMA C-in
            acc[0][s2] = bI; acc[1][s2] = bG; acc[2][s2] = bO;
        }
#pragma unroll
        for (int kt = 0; kt < 4; ++kt) {
            Frag b[2];
#pragma unroll
            for (int s2 = 0; s2 < 2; ++s2)
                b[s2].u = make_uint4(hw0[s2][4*kt], hw0[s2][4*kt+1],
                                     hw0[s2][4*kt+2], hw0[s2][4*kt+3]);
#pragma unroll
            for (int g = 0; g < 3; ++g) {
                const int n = g * 128 + nc * 16 + m;
                Frag a; a.u = w1s[(n << 4) + ((kt * 4 + q) ^ swz)];
#pragma unroll
                for (int s2 = 0; s2 < 2; ++s2)
                    acc[g][s2] = __builtin_amdgcn_mfma_f32_16x16x32_bf16(
                        a.v, b[s2].v, acc[g][s2], 0, 0, 0);
            }
        }
#pragma unroll
        for (int s2 = 0; s2 < 2; ++s2)
#pragma unroll
            for (int u = 0; u < 2; ++u) {
                const f32x2 ip = {acc[0][s2][2*u], acc[0][s2][2*u+1]};
                const f32x2 gp = {acc[1][s2][2*u], acc[1][s2][2*u+1]};
                const f32x2 op = {acc[2][s2][2*u], acc[2][s2][2*u+1]};
                hw1[s2][nc * 2 + u] = lstm_h2(ip, gp, op);
            }
    }

    // ===== Heads: D3 = Wph x h1^T; tile0 rows = policy, tile1 row16 = value =
    f32x4 ap[2], av[2];
    ap[0] = vzero; ap[1] = vzero; av[0] = vzero; av[1] = vzero;
#pragma unroll
    for (int kt = 0; kt < 4; ++kt) {
        Frag a0; a0.u = wph[( m       << 4) + ((kt * 4 + q) ^ swz)];
        Frag a1; a1.u = wph[((16 + m) << 4) + ((kt * 4 + q) ^ swz)];   // (16+m)&7 == m&7
#pragma unroll
        for (int s2 = 0; s2 < 2; ++s2) {
            Frag b; b.u = make_uint4(hw1[s2][4*kt], hw1[s2][4*kt+1],
                                     hw1[s2][4*kt+2], hw1[s2][4*kt+3]);
            ap[s2] = __builtin_amdgcn_mfma_f32_16x16x32_bf16(a0.v, b.v, ap[s2], 0, 0, 0);
            av[s2] = __builtin_amdgcn_mfma_f32_16x16x32_bf16(a1.v, b.v, av[s2], 0, 0, 0);
        }
    }
#pragma unroll
    for (int s2 = 0; s2 < 2; ++s2) {
        const int row = rbase + s2 * 16 + m;
        // policy: D col = batch m, row = action q*4+r -> one dwordx4 per lane
        f32x4 po;
        po[0] = ap[s2][0] + bpr.x; po[1] = ap[s2][1] + bpr.y;
        po[2] = ap[s2][2] + bpr.z; po[3] = ap[s2][3] + bpr.w;
        *reinterpret_cast<f32x4*>(out + (size_t)row * NA + q * 4) = po;
        // value lives at tile1 in-tile row 0 -> q==0, reg 0
        if (q == 0) out[(size_t)BATCH * NA + row] = av[s2][0] + bvv;
    }
}

extern "C" void kernel_launch(void* const* d_in, const int* in_sizes, int n_in,
                              void* d_out, int out_size, void* d_ws, size_t ws_size,
                              hipStream_t stream) {
    // setup_inputs order: x, Wih0, Whh0, bih0, bhh0, Wih1, Whh1, bih1, bhh1, Wp, bp, Wv, bv
    // Whh0 (idx 2) / Whh1 (idx 6) dead (h_prev = 0); f-gate dead (c_prev = 0).
    lstm_fused<<<dim3(NBLK), dim3(TPB), 0, stream>>>(
        (const float*)d_in[0], (const float*)d_in[1],
        (const float*)d_in[3], (const float*)d_in[4],
        (const float*)d_in[5], (const float*)d_in[7],
        (const float*)d_in[8], (const float*)d_in[9],
        (const float*)d_in[10], (const float*)d_in[11],
        (const float*)d_in[12], (float*)d_out);
}